// Round 2
// baseline (52502.710 us; speedup 1.0000x reference)
//
#include <hip/hip_runtime.h>

#define TT 8192
#define HH 200      // hidden size
#define NBH 100     // neurons per half (per recurrence block)
#define ROWS 400    // gate rows per recurrence block (4 gates x 100 neurons)
#define RD 1024     // pre1 ring depth (steps)
#define RDM 1023

typedef unsigned long long u64;
typedef unsigned int u32;

__device__ __forceinline__ float sigmoidf_(float x){ return 1.0f/(1.0f+__expf(-x)); }
__device__ __forceinline__ float tanhf_(float x){
    float e = __expf(2.0f*fabsf(x));
    float r = 1.0f - 2.0f/(e + 1.0f);
    return copysignf(r, x);
}
__device__ __forceinline__ u64 pck(u32 tag, float v){
    return ((u64)tag << 32) | (u64)__float_as_uint(v);
}
__device__ __forceinline__ u64 ald(u64* p){
    return __hip_atomic_load(p, __ATOMIC_RELAXED, __HIP_MEMORY_SCOPE_AGENT);
}
__device__ __forceinline__ void ast(u64* p, u64 v){
    __hip_atomic_store(p, v, __ATOMIC_RELAXED, __HIP_MEMORY_SCOPE_AGENT);
}

// poll up to two tagged slots with both loads kept in flight (one latency)
__device__ __forceinline__ void poll2(u64* a0, u64* a1, bool h1, u32 tag,
                                      float* d0, float* d1){
    u64 v0, v1 = 0;
    for(;;){
        v0 = ald(a0);
        if (h1) v1 = ald(a1);
        if ((u32)(v0>>32) == tag && (!h1 || (u32)(v1>>32) == tag)) break;
    }
    *d0 = __uint_as_float((u32)v0);
    if (h1) *d1 = __uint_as_float((u32)v1);
}

// roles: blockIdx 0,1 = layer0 halves; 2,3 = pre1 halves; 4,5 = layer1 halves
__global__ __launch_bounds__(512, 2)
void lstm_pipe(const float* __restrict__ x,
               const float* __restrict__ Wih0, const float* __restrict__ Whh0,
               const float* __restrict__ bih0, const float* __restrict__ bhh0,
               const float* __restrict__ Wih1, const float* __restrict__ Whh1,
               const float* __restrict__ bih1, const float* __restrict__ bhh1,
               const float* __restrict__ Wout, const float* __restrict__ bout,
               u64* __restrict__ h0s,   // [TT][HH] tagged pairs
               u64* __restrict__ p1r,   // [RD][800] tagged pairs (ring)
               u64* __restrict__ h1x,   // [8][HH] tagged pairs (ring)
               u32* __restrict__ prog,  // [2] layer-1 progress
               float* __restrict__ out)
{
    const int role = blockIdx.x;
    const int tid  = threadIdx.x;

    __shared__ float xs[TT];            // 32 KB, layer-0 only
    __shared__ float h_lds[2][HH];
    __shared__ float s_lds[ROWS];
    __shared__ float p_lds[2][ROWS];    // layer-1 only

    // ================= pre1 streaming stage =================
    if (role == 2 || role == 3) {
        const int half = role - 2, nb = half * NBH;
        int grow = 0; float bs = 0.f;
        float w[HH];
        if (tid < ROWS) {
            const int q = tid / NBH, j = tid % NBH;
            grow = q * HH + nb + j;
            const float* wr = Wih1 + (size_t)grow * HH;
            #pragma unroll
            for (int k = 0; k < HH; ++k) w[k] = wr[k];
            bs = bih1[grow] + bhh1[grow];
        }
        u32 prog_c = 0;
        // preload h0[0]
        if (tid >= 400) {
            const int m = tid - 400;
            const bool h1 = (m + 112 < HH);
            poll2(&h0s[m], &h0s[m + 112], h1, 1u,
                  &h_lds[0][m], &h_lds[0][m + 112]);
        }
        __syncthreads();
        for (int t = 0; t < TT; ++t) {
            if (tid < ROWS) {
                const float4* h4 = (const float4*)h_lds[t & 1];
                float a0=0.f, a1=0.f, a2=0.f, a3=0.f;
                #pragma unroll
                for (int k4 = 0; k4 < 50; ++k4) {
                    float4 hv = h4[k4];
                    a0 += w[4*k4  ] * hv.x;  a1 += w[4*k4+1] * hv.y;
                    a2 += w[4*k4+2] * hv.z;  a3 += w[4*k4+3] * hv.w;
                }
                float a = (a0 + a1) + (a2 + a3) + bs;
                ast(&p1r[(size_t)(t & RDM) * 800 + grow], pck((u32)(t + 1), a));
            } else {
                if (t + 1 < TT) {   // prefetch h0[t+1]
                    const int m = tid - 400;
                    const bool h1 = (m + 112 < HH);
                    poll2(&h0s[(size_t)(t+1)*HH + m], &h0s[(size_t)(t+1)*HH + m + 112],
                          h1, (u32)(t + 2),
                          &h_lds[(t+1)&1][m], &h_lds[(t+1)&1][m + 112]);
                }
                if (tid == 400) {   // backpressure for step t+1's store
                    while ((t + 1) - (int)prog_c >= RD - 32)
                        prog_c = __hip_atomic_load(&prog[half], __ATOMIC_RELAXED,
                                                   __HIP_MEMORY_SCOPE_AGENT);
                }
            }
            __syncthreads();
        }
        return;
    }

    // ================= recurrence stages =================
    const bool L0  = (role < 2);
    const int half = L0 ? role : role - 4;
    const int nb   = half * NBH;
    const int pb   = (1 - half) * NBH;
    const float* Whh = L0 ? Whh0 : Whh1;

    float w[2 * NBH];          // reordered: own k-range first, partner second
    float wih = 0.f, bs = 0.f;
    if (tid < ROWS) {
        const int q = tid / NBH, j = tid % NBH;
        const int grow = q * HH + nb + j;
        const float* wr = Whh + (size_t)grow * HH;
        #pragma unroll
        for (int m = 0; m < NBH; ++m) {
            w[m]       = wr[nb + m];
            w[NBH + m] = wr[pb + m];
        }
        if (L0) { bs = bih0[grow] + bhh0[grow]; wih = Wih0[grow]; }
    }
    if (L0) for (int i = tid; i < TT; i += 512) xs[i] = x[i];
    if (tid < HH) { h_lds[0][tid] = 0.f; h_lds[1][tid] = 0.f; }

    if (!L0 && tid >= 400 && tid < 448) {   // preload pre1[0]
        u64 v[9] = {};
        const int m0 = tid - 400;
        for(;;){
            #pragma unroll
            for (int r = 0; r < 9; ++r) {
                int mm = m0 + 48*r;
                if (mm < ROWS) {
                    int gq = mm / NBH, gj = mm % NBH;
                    v[r] = ald(&p1r[gq * HH + nb + gj]);
                }
            }
            bool ok = true;
            #pragma unroll
            for (int r = 0; r < 9; ++r) {
                int mm = m0 + 48*r;
                if (mm < ROWS && (u32)(v[r]>>32) != 1u) ok = false;
            }
            if (ok) break;
        }
        #pragma unroll
        for (int r = 0; r < 9; ++r) {
            int mm = m0 + 48*r;
            if (mm < ROWS) p_lds[0][mm] = __uint_as_float((u32)v[r]);
        }
    }

    float c = 0.f;
    int cur = 0;
    __syncthreads();

    for (int t = 0; t < TT; ++t) {
        float a0=0.f, a1=0.f, a2=0.f, a3=0.f;
        // ---- P1: own-half FMA  ||  partner-h poll  ||  pre1 prefetch ----
        if (tid < ROWS) {
            const float4* h4 = (const float4*)&h_lds[cur][nb];
            #pragma unroll
            for (int k4 = 0; k4 < 25; ++k4) {
                float4 hv = h4[k4];
                a0 += w[4*k4  ] * hv.x;  a1 += w[4*k4+1] * hv.y;
                a2 += w[4*k4+2] * hv.z;  a3 += w[4*k4+3] * hv.w;
            }
        } else if (tid >= 448) {
            if (t > 0) {
                const int l = tid - 448;
                const bool h1 = (l + 64 < NBH);
                u64* base = L0 ? &h0s[(size_t)(t-1)*HH] : &h1x[(size_t)((t-1)&7)*HH];
                poll2(base + pb + l, base + pb + l + 64, h1, (u32)t,
                      &h_lds[cur][pb + l], &h_lds[cur][pb + l + 64]);
            }
        } else {   // lanes 400..447: layer-1 pre1[t+1] prefetch
            if (!L0 && t + 1 < TT) {
                u64 v[9] = {};
                const int m0 = tid - 400;
                const u32 tg = (u32)(t + 2);
                u64* slot = &p1r[(size_t)((t+1) & RDM) * 800];
                for(;;){
                    #pragma unroll
                    for (int r = 0; r < 9; ++r) {
                        int mm = m0 + 48*r;
                        if (mm < ROWS) {
                            int gq = mm / NBH, gj = mm % NBH;
                            v[r] = ald(slot + gq * HH + nb + gj);
                        }
                    }
                    bool ok = true;
                    #pragma unroll
                    for (int r = 0; r < 9; ++r) {
                        int mm = m0 + 48*r;
                        if (mm < ROWS && (u32)(v[r]>>32) != tg) ok = false;
                    }
                    if (ok) break;
                }
                #pragma unroll
                for (int r = 0; r < 9; ++r) {
                    int mm = m0 + 48*r;
                    if (mm < ROWS) p_lds[(t+1)&1][mm] = __uint_as_float((u32)v[r]);
                }
            }
        }
        __syncthreads();
        // ---- P2: partner-half FMA + finalize pre-activation ----
        if (tid < ROWS) {
            const float4* h4 = (const float4*)&h_lds[cur][pb];
            #pragma unroll
            for (int k4 = 0; k4 < 25; ++k4) {
                float4 hv = h4[k4];
                a0 += w[NBH+4*k4  ] * hv.x;  a1 += w[NBH+4*k4+1] * hv.y;
                a2 += w[NBH+4*k4+2] * hv.z;  a3 += w[NBH+4*k4+3] * hv.w;
            }
            float a = (a0 + a1) + (a2 + a3);
            if (L0) a += xs[t] * wih + bs;
            else    a += p_lds[t & 1][tid];
            s_lds[tid] = a;
        }
        __syncthreads();
        // ---- P3: gates + state update (threads 0..99) ----
        if (tid < NBH) {
            float ig = sigmoidf_(s_lds[tid]);
            float fg = sigmoidf_(s_lds[NBH + tid]);
            float gg = tanhf_  (s_lds[2*NBH + tid]);
            float og = sigmoidf_(s_lds[3*NBH + tid]);
            c = fg * c + ig * gg;
            float h = og * tanhf_(c);
            h_lds[cur ^ 1][nb + tid] = h;
            if (L0) ast(&h0s[(size_t)t*HH + nb + tid],      pck((u32)(t+1), h));
            else    ast(&h1x[(size_t)(t&7)*HH + nb + tid],  pck((u32)(t+1), h));
        }
        __syncthreads();
        if (!L0 && tid == 0 && (t & 7) == 7)
            __hip_atomic_store(&prog[half], (u32)(t + 1), __ATOMIC_RELAXED,
                               __HIP_MEMORY_SCOPE_AGENT);
        cur ^= 1;
    }

    // ---- linear head on final h1 (block 4 only) ----
    if (!L0 && half == 0) {
        if (tid >= 448) {
            const int l = tid - 448;
            const bool h1 = (l + 64 < NBH);
            u64* base = &h1x[(size_t)((TT-1)&7)*HH];
            poll2(base + pb + l, base + pb + l + 64, h1, (u32)TT,
                  &h_lds[cur][pb + l], &h_lds[cur][pb + l + 64]);
        }
        __syncthreads();
        if (tid < 64) {
            float s = 0.f;
            for (int k = tid; k < HH; k += 64) s += h_lds[cur][k] * Wout[k];
            #pragma unroll
            for (int off = 32; off > 0; off >>= 1) s += __shfl_down(s, off);
            if (tid == 0) out[0] = s + bout[0];
        }
    }
}

extern "C" void kernel_launch(void* const* d_in, const int* in_sizes, int n_in,
                              void* d_out, int out_size, void* d_ws, size_t ws_size,
                              hipStream_t stream) {
    const float* x    = (const float*)d_in[0];
    const float* Wih0 = (const float*)d_in[1];
    const float* Whh0 = (const float*)d_in[2];
    const float* bih0 = (const float*)d_in[3];
    const float* bhh0 = (const float*)d_in[4];
    const float* Wih1 = (const float*)d_in[5];
    const float* Whh1 = (const float*)d_in[6];
    const float* bih1 = (const float*)d_in[7];
    const float* bhh1 = (const float*)d_in[8];
    const float* Wout = (const float*)d_in[9];
    const float* bout = (const float*)d_in[10];
    float* out = (float*)d_out;

    char* ws = (char*)d_ws;
    // layout: h0s 13,107,200 | p1r 6,553,600 | h1x 12,800 | prog 64
    u64* h0s  = (u64*)ws;
    u64* p1r  = (u64*)(ws + 13107200);
    u64* h1x  = (u64*)(ws + 13107200 + 6553600);
    u32* prog = (u32*)(ws + 13107200 + 6553600 + 12800);

    // clear all tag/progress state every launch (graph-safe, removes
    // cross-replay stale-tag hazard)
    hipMemsetAsync(ws, 0, 13107200 + 6553600 + 12800 + 64, stream);

    hipLaunchKernelGGL(lstm_pipe, dim3(6), dim3(512), 0, stream,
        x, Wih0, Whh0, bih0, bhh0, Wih1, Whh1, bih1, bhh1, Wout, bout,
        h0s, p1r, h1x, prog, out);
}

// Round 3
// 18000.351 us; speedup vs baseline: 2.9168x; 2.9168x over previous
//
#include <hip/hip_runtime.h>

#define TT 8192
#define HH 200
#define NPB 25      // neurons per recurrence block (8 blocks/layer)
#define RD 1024     // pre1 ring depth (steps)
#define RDM 1023
#define BPWIN 900   // backpressure window (< RD - prog staleness)

typedef unsigned long long u64;
typedef unsigned int u32;

__device__ __forceinline__ float sigmoidf_(float x){ return 1.0f/(1.0f+__expf(-x)); }
__device__ __forceinline__ float tanhf_(float x){
    float e = __expf(2.0f*fabsf(x));
    float r = 1.0f - 2.0f/(e + 1.0f);
    return copysignf(r, x);
}
__device__ __forceinline__ u64 pck(u32 tag, float v){
    return ((u64)tag << 32) | (u64)__float_as_uint(v);
}
__device__ __forceinline__ u64 ald(const u64* p){
    return __hip_atomic_load((u64*)p, __ATOMIC_RELAXED, __HIP_MEMORY_SCOPE_AGENT);
}
__device__ __forceinline__ void ast(u64* p, u64 v){
    __hip_atomic_store(p, v, __ATOMIC_RELAXED, __HIP_MEMORY_SCOPE_AGENT);
}

// 64 lanes (m = tid-448) fetch 200 tagged values into dst (batched in flight)
__device__ __forceinline__ void poll200(const u64* base, u32 tag, float* dst, int m){
    u64 v0, v1, v2, v3 = 0;
    const bool g3 = (m < 8);
    for(;;){
        v0 = ald(base + m);
        v1 = ald(base + m + 64);
        v2 = ald(base + m + 128);
        if (g3) v3 = ald(base + m + 192);
        if ((u32)(v0>>32)==tag && (u32)(v1>>32)==tag && (u32)(v2>>32)==tag &&
            (!g3 || (u32)(v3>>32)==tag)) break;
    }
    dst[m]       = __uint_as_float((u32)v0);
    dst[m + 64]  = __uint_as_float((u32)v1);
    dst[m + 128] = __uint_as_float((u32)v2);
    if (g3) dst[m + 192] = __uint_as_float((u32)v3);
}

// 48 lanes (m = tid-400) fetch this block's 100 pre1 rows from a ring slot
__device__ __forceinline__ void pollP(const u64* slot, u32 tag, float* dst,
                                      int m, int nb){
    const int mm0 = m, mm1 = m + 48, mm2 = m + 96;
    const int i0 = (mm0/NPB)*HH + nb + mm0%NPB;
    const int i1 = (mm1/NPB)*HH + nb + mm1%NPB;
    const bool g2 = (mm2 < 100);
    const int i2 = g2 ? (mm2/NPB)*HH + nb + mm2%NPB : 0;
    u64 v0, v1, v2 = 0;
    for(;;){
        v0 = ald(slot + i0);
        v1 = ald(slot + i1);
        if (g2) v2 = ald(slot + i2);
        if ((u32)(v0>>32)==tag && (u32)(v1>>32)==tag &&
            (!g2 || (u32)(v2>>32)==tag)) break;
    }
    dst[mm0] = __uint_as_float((u32)v0);
    dst[mm1] = __uint_as_float((u32)v1);
    if (g2) dst[mm2] = __uint_as_float((u32)v2);
}

// roles: 0-7 layer-0 recurrence, 8-15 pre1 stream, 16-23 layer-1 recurrence.
// Each block: 100 gate rows (4 gates x 25 neurons), 4 lanes/row (K=50 each,
// w[50] register-resident), shfl_xor reduce. Tagged-atomic exchange.
__global__ __launch_bounds__(512, 1)
void lstm_pipe(const float* __restrict__ x,
               const float* __restrict__ Wih0, const float* __restrict__ Whh0,
               const float* __restrict__ bih0, const float* __restrict__ bhh0,
               const float* __restrict__ Wih1, const float* __restrict__ Whh1,
               const float* __restrict__ bih1, const float* __restrict__ bhh1,
               const float* __restrict__ Wout, const float* __restrict__ bout,
               u64* __restrict__ h0s,   // [TT][HH] tagged
               u64* __restrict__ p1r,   // [RD][800] tagged ring
               u64* __restrict__ h1x,   // [64][HH] tagged ring
               u32* __restrict__ prog,  // [1] layer-1 progress
               float* __restrict__ out)
{
    const int role = blockIdx.x;
    const int tid  = threadIdx.x;

    __shared__ float xs[TT];          // 32 KB (used by L0 roles only)
    __shared__ float h_lds[HH];
    __shared__ float s_lds[100];
    __shared__ float p_lds[2][100];   // L1 only

    const int lg = tid >> 2;          // row 0..127 (100 used)
    const int kq = tid & 3;           // K-quarter
    const bool fa = (tid < 400);

    // ---------------- pre1 streaming stage ----------------
    if (role >= 8 && role < 16) {
        const int nb = (role - 8) * NPB;
        int grow = 0; float bs = 0.f;
        float w[50];
        if (fa) {
            const int q = lg / NPB, j = lg % NPB;
            grow = q * HH + nb + j;
            const float* wr = Wih1 + (size_t)grow * HH + kq * 50;
            #pragma unroll
            for (int k = 0; k < 50; ++k) w[k] = wr[k];
            if (kq == 0) bs = bih1[grow] + bhh1[grow];
        }
        u32 prog_c = 0;
        __syncthreads();
        for (int t = 0; t < TT; ++t) {
            if (tid >= 448) {
                poll200(&h0s[(size_t)t * HH], (u32)(t + 1), h_lds, tid - 448);
            } else if (tid == 400) {
                while ((int)(t + 1) - (int)prog_c >= BPWIN) {
                    __builtin_amdgcn_s_sleep(2);
                    prog_c = __hip_atomic_load(prog, __ATOMIC_RELAXED,
                                               __HIP_MEMORY_SCOPE_AGENT);
                }
            }
            __syncthreads();
            if (fa) {
                float a0 = 0.f, a1 = 0.f;
                const float2* h2 = (const float2*)(h_lds + kq * 50);
                #pragma unroll
                for (int m2 = 0; m2 < 25; ++m2) {
                    float2 hv = h2[m2];
                    a0 += w[2*m2]   * hv.x;
                    a1 += w[2*m2+1] * hv.y;
                }
                float s = a0 + a1;
                s += __shfl_xor(s, 1);
                s += __shfl_xor(s, 2);
                if (kq == 0)
                    ast(&p1r[(size_t)(t & RDM) * 800 + grow],
                        pck((u32)(t + 1), s + bs));
            }
            __syncthreads();
        }
        return;
    }

    // ---------------- recurrence stages ----------------
    const bool L0 = (role < 8);
    const int b  = L0 ? role : role - 16;
    const int nb = b * NPB;
    const float* Whh = L0 ? Whh0 : Whh1;

    int grow = 0; float wih = 0.f, bs = 0.f;
    float w[50];
    if (fa) {
        const int q = lg / NPB, j = lg % NPB;
        grow = q * HH + nb + j;
        const float* wr = Whh + (size_t)grow * HH + kq * 50;
        #pragma unroll
        for (int k = 0; k < 50; ++k) w[k] = wr[k];
        if (L0 && kq == 0) { bs = bih0[grow] + bhh0[grow]; wih = Wih0[grow]; }
    }
    if (L0) for (int i = tid; i < TT; i += 512) xs[i] = x[i];
    if (tid < HH) h_lds[tid] = 0.f;

    if (!L0 && tid >= 400 && tid < 448)       // preload pre1[0]
        pollP(p1r, 1u, p_lds[0], tid - 400, nb);

    float c = 0.f;
    __syncthreads();

    for (int t = 0; t < TT; ++t) {
        // ---- phase A: FMA on h[t-1]; L1 lanes 400-447 prefetch pre1[t+1] ----
        if (fa) {
            float a0 = 0.f, a1 = 0.f;
            const float2* h2 = (const float2*)(h_lds + kq * 50);
            #pragma unroll
            for (int m2 = 0; m2 < 25; ++m2) {
                float2 hv = h2[m2];
                a0 += w[2*m2]   * hv.x;
                a1 += w[2*m2+1] * hv.y;
            }
            float s = a0 + a1;
            s += __shfl_xor(s, 1);
            s += __shfl_xor(s, 2);
            if (kq == 0) {
                if (L0) s_lds[lg] = s + xs[t] * wih + bs;
                else    s_lds[lg] = s + p_lds[t & 1][lg];
            }
        } else if (!L0 && tid < 448) {
            if (t + 1 < TT)
                pollP(&p1r[(size_t)((t + 1) & RDM) * 800], (u32)(t + 2),
                      p_lds[(t + 1) & 1], tid - 400, nb);
        }
        __syncthreads();
        // ---- phase B: gates+store (lanes<25) || poll h[t] (lanes>=448) ----
        if (tid < NPB) {
            float ig = sigmoidf_(s_lds[tid]);
            float fg = sigmoidf_(s_lds[NPB + tid]);
            float gg = tanhf_  (s_lds[2*NPB + tid]);
            float og = sigmoidf_(s_lds[3*NPB + tid]);
            c = fg * c + ig * gg;
            float h = og * tanhf_(c);
            if (L0) ast(&h0s[(size_t)t * HH + nb + tid], pck((u32)(t+1), h));
            else    ast(&h1x[(size_t)(t & 63) * HH + nb + tid], pck((u32)(t+1), h));
        } else if (tid >= 448) {
            const u64* base = L0 ? &h0s[(size_t)t * HH]
                                 : &h1x[(size_t)(t & 63) * HH];
            poll200(base, (u32)(t + 1), h_lds, tid - 448);
        } else if (!L0 && b == 0 && tid == 32 && (t & 63) == 63) {
            __hip_atomic_store(prog, (u32)(t + 1), __ATOMIC_RELAXED,
                               __HIP_MEMORY_SCOPE_AGENT);
        }
        __syncthreads();
    }

    // ---- linear head on final h1 (L1 block 0) ----
    if (!L0 && b == 0 && tid < 64) {
        float s2 = 0.f;
        for (int k = tid; k < HH; k += 64) s2 += h_lds[k] * Wout[k];
        #pragma unroll
        for (int off = 32; off > 0; off >>= 1) s2 += __shfl_down(s2, off);
        if (tid == 0) out[0] = s2 + bout[0];
    }
}

extern "C" void kernel_launch(void* const* d_in, const int* in_sizes, int n_in,
                              void* d_out, int out_size, void* d_ws, size_t ws_size,
                              hipStream_t stream) {
    const float* x    = (const float*)d_in[0];
    const float* Wih0 = (const float*)d_in[1];
    const float* Whh0 = (const float*)d_in[2];
    const float* bih0 = (const float*)d_in[3];
    const float* bhh0 = (const float*)d_in[4];
    const float* Wih1 = (const float*)d_in[5];
    const float* Whh1 = (const float*)d_in[6];
    const float* bih1 = (const float*)d_in[7];
    const float* bhh1 = (const float*)d_in[8];
    const float* Wout = (const float*)d_in[9];
    const float* bout = (const float*)d_in[10];
    float* out = (float*)d_out;

    char* ws = (char*)d_ws;
    // h0s 13,107,200 | p1r 6,553,600 | h1x 102,400 | prog 64
    u64* h0s  = (u64*)ws;
    u64* p1r  = (u64*)(ws + 13107200);
    u64* h1x  = (u64*)(ws + 19660800);
    u32* prog = (u32*)(ws + 19763200);

    // clear all tags/progress every launch (graph-safe, deterministic)
    hipMemsetAsync(ws, 0, 19763264, stream);

    hipLaunchKernelGGL(lstm_pipe, dim3(24), dim3(512), 0, stream,
        x, Wih0, Whh0, bih0, bhh0, Wih1, Whh1, bih1, bhh1, Wout, bout,
        h0s, p1r, h1x, prog, out);
}